// Round 1
// baseline (1842.595 us; speedup 1.0000x reference)
//
#include <hip/hip_runtime.h>
#include <math.h>

#define NB 4096
#define NN 256
#define NF 16
#define NK 64
#define DIN 19
#define DM 128
#define DFF 256

__global__ __launch_bounds__(256, 2) void itemblock_kernel(
    const float* __restrict__ x, const int* __restrict__ idxs,
    const float* __restrict__ origin, const float* __restrict__ direction,
    const float* __restrict__ norm_count, const float* __restrict__ norm_mean,
    const float* __restrict__ norm_sqsum, const float* __restrict__ W_emb,
    const float* __restrict__ b_emb, const float* __restrict__ ln1g,
    const float* __restrict__ ln1b, const float* __restrict__ W1,
    const float* __restrict__ b1, const float* __restrict__ W2,
    const float* __restrict__ b2, const float* __restrict__ ln2g,
    const float* __restrict__ ln2b,
    float* __restrict__ out, float* __restrict__ outrel, float* __restrict__ outmask)
{
    __shared__ unsigned long long s_keys[NN];   // 2048 B
    __shared__ float s_xn[NK][20];              // 5120 B
    __shared__ float s_keep[NK];                // 256 B
    __shared__ float s_h[NK][132];              // 33792 B (pad 132: conflict-free b128 reads)
    __shared__ float s_h2c[NK][68];             // 17408 B (64-col h2 chunk)
    // total 58,624 B -> 2 blocks/CU

    const int b = blockIdx.x;
    const int t = threadIdx.x;

    const float dirx = direction[b*2+0], diry = direction[b*2+1];
    const float ang = -atan2f(diry, dirx);
    const float cr = cosf(ang), sr = sinf(ang);
    const float ox = origin[b*2+0], oy = origin[b*2+1];

    // ---- phase 1: per-candidate sort keys (exactly matches jax f32 key math) ----
    {
        const int j = idxs[b*NN + t];
        const float4 xr = *reinterpret_cast<const float4*>(x + (size_t)j*NF);
        const float dx = xr.x - ox, dy = xr.y - oy;
        const float r0 = cr*dx - sr*dy;
        const float r1 = sr*dx + cr*dy;
        const float dist = sqrtf(r0*r0 + r1*r1);
        const float key = -dist - ((xr.z == 0.0f) ? 1e8f : 0.0f);
        unsigned u = __float_as_uint(key);
        u = (u & 0x80000000u) ? ~u : (u | 0x80000000u);   // monotonic float->uint
        // ascending composite == descending key, ties -> lower position first (top_k semantics)
        s_keys[t] = ((unsigned long long)(~u) << 32) | (unsigned)t;
    }
    __syncthreads();

    // ---- phase 2: bitonic sort of 256 composites, ascending ----
    for (int sz = 2; sz <= NN; sz <<= 1) {
        for (int st = sz >> 1; st > 0; st >>= 1) {
            const int ixj = t ^ st;
            if (ixj > t) {
                const unsigned long long a = s_keys[t];
                const unsigned long long c = s_keys[ixj];
                const bool up = ((t & sz) == 0);
                if ((a > c) == up) { s_keys[t] = c; s_keys[ixj] = a; }
            }
            __syncthreads();
        }
    }

    // ---- phase 3: rebuild features for the selected 64, write relpos/mask ----
    if (t < NK) {
        const int p = (int)(s_keys[t] & 0xFFFFFFFFull);
        const int j = idxs[b*NN + p];
        const float4* xrow = reinterpret_cast<const float4*>(x + (size_t)j*NF);
        const float4 a0 = xrow[0], a1 = xrow[1], a2 = xrow[2], a3 = xrow[3];
        float xc[DIN];
        xc[0]=a0.x; xc[1]=a0.y; xc[2]=a0.z; xc[3]=a0.w;
        xc[4]=a1.x; xc[5]=a1.y; xc[6]=a1.z; xc[7]=a1.w;
        xc[8]=a2.x; xc[9]=a2.y; xc[10]=a2.z; xc[11]=a2.w;
        xc[12]=a3.x; xc[13]=a3.y; xc[14]=a3.z; xc[15]=a3.w;
        const float dx = xc[0]-ox, dy = xc[1]-oy;
        const float r0 = cr*dx - sr*dy;
        const float r1 = sr*dx + cr*dy;
        const float dist = sqrtf(r0*r0 + r1*r1);
        const float inv = 1.0f / (dist + 1e-8f);
        xc[16] = r0*inv; xc[17] = r1*inv; xc[18] = sqrtf(dist);
        const float cnt = norm_count[0];
        #pragma unroll
        for (int f = 0; f < DIN; ++f) {
            float sd = sqrtf(norm_sqsum[f] / (cnt - 1.0f));
            sd = (sd == 0.0f) ? 1.0f : sd;
            float v = (xc[f] - norm_mean[f]) / sd;
            v = fminf(fmaxf(v, -5.0f), 5.0f);
            s_xn[t][f] = v;
        }
        const bool msk = (xc[2] == 0.0f);
        outrel[((size_t)b*NK + t)*2 + 0] = r0;
        outrel[((size_t)b*NK + t)*2 + 1] = r1;
        outmask[(size_t)b*NK + t] = msk ? 1.0f : 0.0f;
        s_keep[t] = msk ? 0.0f : 1.0f;
    }
    __syncthreads();

    // thread tile: rows k0..k0+3, cols per-phase
    const int rb = t >> 4, cb = t & 15;
    const int k0 = rb * 4;

    // ---- phase 4: h1 = LN1(relu(xn @ W_emb^T + b_emb)), cols = cb*8..cb*8+7 ----
    float acc1[4][8];
    #pragma unroll
    for (int i = 0; i < 8; ++i) {
        const float bb = b_emb[cb*8 + i];
        #pragma unroll
        for (int r = 0; r < 4; ++r) acc1[r][i] = bb;
    }
    for (int f = 0; f < DIN; ++f) {
        float xnv[4];
        #pragma unroll
        for (int r = 0; r < 4; ++r) xnv[r] = s_xn[k0+r][f];
        #pragma unroll
        for (int i = 0; i < 8; ++i) {
            const float w = W_emb[(cb*8 + i)*DIN + f];
            #pragma unroll
            for (int r = 0; r < 4; ++r) acc1[r][i] = fmaf(xnv[r], w, acc1[r][i]);
        }
    }
    #pragma unroll
    for (int r = 0; r < 4; ++r) {
        float ps = 0.0f, pq = 0.0f;
        #pragma unroll
        for (int i = 0; i < 8; ++i) {
            const float v = fmaxf(acc1[r][i], 0.0f);
            acc1[r][i] = v;
            ps += v; pq += v*v;
        }
        #pragma unroll
        for (int ml = 1; ml <= 8; ml <<= 1) {   // reduce over the 16 lanes sharing the row
            ps += __shfl_xor(ps, ml, 64);
            pq += __shfl_xor(pq, ml, 64);
        }
        const float mu = ps * (1.0f/128.0f);
        const float var = pq * (1.0f/128.0f) - mu*mu;
        const float rstd = rsqrtf(var + 1e-5f);
        #pragma unroll
        for (int i = 0; i < 8; ++i) {
            const int m = cb*8 + i;
            s_h[k0+r][m] = (acc1[r][i] - mu) * rstd * ln1g[m] + ln1b[m];
        }
    }
    __syncthreads();

    // ---- phase 5: h2 = relu(h@W1^T+b1) in 64-col chunks; acc3 += h2@W2^T ----
    float acc3[4][8];
    #pragma unroll
    for (int i = 0; i < 8; ++i) {
        const float bb = b2[cb*8 + i];
        #pragma unroll
        for (int r = 0; r < 4; ++r) acc3[r][i] = bb;
    }
    for (int cc = 0; cc < 4; ++cc) {
        float acc2[4][4];
        #pragma unroll
        for (int jj = 0; jj < 4; ++jj) {
            const float bb = b1[cc*64 + cb*4 + jj];
            #pragma unroll
            for (int r = 0; r < 4; ++r) acc2[r][jj] = bb;
        }
        for (int f4 = 0; f4 < 32; ++f4) {
            float4 h4[4];
            #pragma unroll
            for (int r = 0; r < 4; ++r)
                h4[r] = *reinterpret_cast<const float4*>(&s_h[k0+r][f4*4]);
            #pragma unroll
            for (int jj = 0; jj < 4; ++jj) {
                const float4 w = *reinterpret_cast<const float4*>(
                    &W1[((size_t)(cc*64 + cb*4 + jj))*DM + f4*4]);
                #pragma unroll
                for (int r = 0; r < 4; ++r)
                    acc2[r][jj] = fmaf(h4[r].x, w.x, fmaf(h4[r].y, w.y,
                                  fmaf(h4[r].z, w.z, fmaf(h4[r].w, w.w, acc2[r][jj]))));
            }
        }
        __syncthreads();   // previous chunk's consumers done before overwrite
        #pragma unroll
        for (int r = 0; r < 4; ++r) {
            float4 v;
            v.x = fmaxf(acc2[r][0], 0.0f);
            v.y = fmaxf(acc2[r][1], 0.0f);
            v.z = fmaxf(acc2[r][2], 0.0f);
            v.w = fmaxf(acc2[r][3], 0.0f);
            *reinterpret_cast<float4*>(&s_h2c[k0+r][cb*4]) = v;
        }
        __syncthreads();
        for (int c4 = 0; c4 < 16; ++c4) {
            float4 rh[4];
            #pragma unroll
            for (int r = 0; r < 4; ++r)
                rh[r] = *reinterpret_cast<const float4*>(&s_h2c[k0+r][c4*4]);
            #pragma unroll
            for (int i = 0; i < 8; ++i) {
                const float4 w = *reinterpret_cast<const float4*>(
                    &W2[((size_t)(cb*8 + i))*DFF + cc*64 + c4*4]);
                #pragma unroll
                for (int r = 0; r < 4; ++r)
                    acc3[r][i] = fmaf(rh[r].x, w.x, fmaf(rh[r].y, w.y,
                                 fmaf(rh[r].z, w.z, fmaf(rh[r].w, w.w, acc3[r][i]))));
            }
        }
    }

    // ---- phase 6: residual + LN2 + mask + coalesced store ----
    #pragma unroll
    for (int r = 0; r < 4; ++r) {
        float hv[8];
        float ps = 0.0f, pq = 0.0f;
        #pragma unroll
        for (int i = 0; i < 8; ++i) {
            const float v = s_h[k0+r][cb*8 + i] + fmaxf(acc3[r][i], 0.0f);
            hv[i] = v; ps += v; pq += v*v;
        }
        #pragma unroll
        for (int ml = 1; ml <= 8; ml <<= 1) {
            ps += __shfl_xor(ps, ml, 64);
            pq += __shfl_xor(pq, ml, 64);
        }
        const float mu = ps * (1.0f/128.0f);
        const float var = pq * (1.0f/128.0f) - mu*mu;
        const float rstd = rsqrtf(var + 1e-5f);
        const float keep = s_keep[k0+r];
        const int m0 = cb*8;
        float4 o0, o1;
        o0.x = ((hv[0]-mu)*rstd*ln2g[m0+0] + ln2b[m0+0]) * keep;
        o0.y = ((hv[1]-mu)*rstd*ln2g[m0+1] + ln2b[m0+1]) * keep;
        o0.z = ((hv[2]-mu)*rstd*ln2g[m0+2] + ln2b[m0+2]) * keep;
        o0.w = ((hv[3]-mu)*rstd*ln2g[m0+3] + ln2b[m0+3]) * keep;
        o1.x = ((hv[4]-mu)*rstd*ln2g[m0+4] + ln2b[m0+4]) * keep;
        o1.y = ((hv[5]-mu)*rstd*ln2g[m0+5] + ln2b[m0+5]) * keep;
        o1.z = ((hv[6]-mu)*rstd*ln2g[m0+6] + ln2b[m0+6]) * keep;
        o1.w = ((hv[7]-mu)*rstd*ln2g[m0+7] + ln2b[m0+7]) * keep;
        const size_t base = ((size_t)b*NK + (k0+r))*DM + m0;
        *reinterpret_cast<float4*>(&out[base])     = o0;
        *reinterpret_cast<float4*>(&out[base + 4]) = o1;
    }
}

extern "C" void kernel_launch(void* const* d_in, const int* in_sizes, int n_in,
                              void* d_out, int out_size, void* d_ws, size_t ws_size,
                              hipStream_t stream) {
    const float* x        = (const float*)d_in[0];
    const int*   idxs     = (const int*)  d_in[1];
    const float* origin   = (const float*)d_in[2];
    const float* direction= (const float*)d_in[3];
    const float* ncount   = (const float*)d_in[4];
    const float* nmean    = (const float*)d_in[5];
    const float* nsq      = (const float*)d_in[6];
    const float* W_emb    = (const float*)d_in[7];
    const float* b_emb    = (const float*)d_in[8];
    const float* ln1g     = (const float*)d_in[9];
    const float* ln1b     = (const float*)d_in[10];
    const float* W1       = (const float*)d_in[11];
    const float* b1       = (const float*)d_in[12];
    const float* W2       = (const float*)d_in[13];
    const float* b2       = (const float*)d_in[14];
    const float* ln2g     = (const float*)d_in[15];
    const float* ln2b     = (const float*)d_in[16];

    float* out     = (float*)d_out;
    float* outrel  = out    + (size_t)NB*NK*DM;
    float* outmask = outrel + (size_t)NB*NK*2;

    itemblock_kernel<<<NB, 256, 0, stream>>>(x, idxs, origin, direction, ncount,
        nmean, nsq, W_emb, b_emb, ln1g, ln1b, W1, b1, W2, b2, ln2g, ln2b,
        out, outrel, outmask);
}

// Round 2
// 278.086 us; speedup vs baseline: 6.6260x; 6.6260x over previous
//
#include <hip/hip_runtime.h>
#include <math.h>

#define NB 4096
#define NN 256
#define NF 16
#define NK 64
#define DIN 19
#define DM 128
#define DFF 256

using short8 = __attribute__((ext_vector_type(8))) short;
using f32x4  = __attribute__((ext_vector_type(4))) float;

__device__ inline ushort f2bf(float f) {
    unsigned u = __float_as_uint(f);
    return (ushort)((u + 0x7fffu + ((u >> 16) & 1u)) >> 16);
}
__device__ inline float bf2f(ushort h) {
    return __uint_as_float(((unsigned)h) << 16);
}

// ---- pre-kernel: convert weights to bf16 in workspace ----
// WembB: [128][32] (K padded 19->32 with zeros), W1B: [256][128], W2B: [128][256]
__global__ void convert_weights(const float* __restrict__ W_emb,
                                const float* __restrict__ W1,
                                const float* __restrict__ W2,
                                ushort* __restrict__ WembB,
                                ushort* __restrict__ W1B,
                                ushort* __restrict__ W2B) {
    const int i = blockIdx.x * 256 + threadIdx.x;   // 0..32767
    if (i < DM * 32) {
        const int n = i >> 5, k = i & 31;
        WembB[i] = f2bf(k < DIN ? W_emb[n * DIN + k] : 0.0f);
    }
    W1B[i] = f2bf(W1[i]);   // 256*128 = 32768
    W2B[i] = f2bf(W2[i]);   // 128*256 = 32768
}

__global__ __launch_bounds__(256, 4) void itemblock_kernel(
    const float* __restrict__ x, const int* __restrict__ idxs,
    const float* __restrict__ origin, const float* __restrict__ direction,
    const float* __restrict__ norm_count, const float* __restrict__ norm_mean,
    const float* __restrict__ norm_sqsum,
    const float* __restrict__ b_emb, const float* __restrict__ ln1g,
    const float* __restrict__ ln1b, const float* __restrict__ b1,
    const float* __restrict__ b2, const float* __restrict__ ln2g,
    const float* __restrict__ ln2b,
    const ushort* __restrict__ WembB, const ushort* __restrict__ W1B,
    const ushort* __restrict__ W2B,
    float* __restrict__ out, float* __restrict__ outrel, float* __restrict__ outmask)
{
    // s_h2c doubles as the sort-key buffer (keys dead before first h2c write)
    __shared__ __align__(16) ushort s_h2c[NK][136];   // 17408 B
    __shared__ __align__(16) ushort s_h1[NK][136];    // 17408 B
    __shared__ __align__(16) ushort s_xn[NK][40];     //  5120 B  (col 19 = keep flag)
    // total 39,936 B -> 4 blocks/CU
    unsigned long long* s_keys = (unsigned long long*)&s_h2c[0][0];

    const int b = blockIdx.x;
    const int t = threadIdx.x;

    // zero s_xn (pad cols must be 0: they hit zero W rows, avoid NaN*0)
    for (int i = t; i < NK * 40 / 2; i += 256) ((unsigned*)s_xn)[i] = 0u;

    const float dirx = direction[b*2+0], diry = direction[b*2+1];
    const float ang = -atan2f(diry, dirx);
    const float cr = cosf(ang), sr = sinf(ang);
    const float ox = origin[b*2+0], oy = origin[b*2+1];

    // ---- phase 1: per-candidate sort keys ----
    {
        const int j = idxs[b*NN + t];
        const float4 xr = *reinterpret_cast<const float4*>(x + (size_t)j*NF);
        const float dx = xr.x - ox, dy = xr.y - oy;
        const float r0 = cr*dx - sr*dy;
        const float r1 = sr*dx + cr*dy;
        const float dist = sqrtf(r0*r0 + r1*r1);
        const float key = -dist - ((xr.z == 0.0f) ? 1e8f : 0.0f);
        unsigned u = __float_as_uint(key);
        u = (u & 0x80000000u) ? ~u : (u | 0x80000000u);
        s_keys[t] = ((unsigned long long)(~u) << 32) | (unsigned)t;
    }
    __syncthreads();

    // ---- phase 2: bitonic sort (ascending composite == top_k order) ----
    for (int sz = 2; sz <= NN; sz <<= 1) {
        for (int st = sz >> 1; st > 0; st >>= 1) {
            const int ixj = t ^ st;
            if (ixj > t) {
                const unsigned long long a = s_keys[t];
                const unsigned long long c = s_keys[ixj];
                const bool up = ((t & sz) == 0);
                if ((a > c) == up) { s_keys[t] = c; s_keys[ixj] = a; }
            }
            __syncthreads();
        }
    }

    // ---- phase 3: features for selected 64 -> bf16 s_xn; relpos/mask out ----
    if (t < NK) {
        const int p = (int)(s_keys[t] & 0xFFFFFFFFull);
        const int j = idxs[b*NN + p];
        const float4* xrow = reinterpret_cast<const float4*>(x + (size_t)j*NF);
        const float4 a0 = xrow[0], a1 = xrow[1], a2 = xrow[2], a3 = xrow[3];
        float xc[DIN];
        xc[0]=a0.x; xc[1]=a0.y; xc[2]=a0.z; xc[3]=a0.w;
        xc[4]=a1.x; xc[5]=a1.y; xc[6]=a1.z; xc[7]=a1.w;
        xc[8]=a2.x; xc[9]=a2.y; xc[10]=a2.z; xc[11]=a2.w;
        xc[12]=a3.x; xc[13]=a3.y; xc[14]=a3.z; xc[15]=a3.w;
        const float dx = xc[0]-ox, dy = xc[1]-oy;
        const float r0 = cr*dx - sr*dy;
        const float r1 = sr*dx + cr*dy;
        const float dist = sqrtf(r0*r0 + r1*r1);
        const float inv = 1.0f / (dist + 1e-8f);
        xc[16] = r0*inv; xc[17] = r1*inv; xc[18] = sqrtf(dist);
        const float cnt = norm_count[0];
        #pragma unroll
        for (int f = 0; f < DIN; ++f) {
            float sd = sqrtf(norm_sqsum[f] / (cnt - 1.0f));
            sd = (sd == 0.0f) ? 1.0f : sd;
            float v = (xc[f] - norm_mean[f]) / sd;
            v = fminf(fmaxf(v, -5.0f), 5.0f);
            s_xn[t][f] = f2bf(v);
        }
        const bool msk = (xc[2] == 0.0f);
        s_xn[t][19] = f2bf(msk ? 0.0f : 1.0f);   // keep flag (exact in bf16)
        outrel[((size_t)b*NK + t)*2 + 0] = r0;
        outrel[((size_t)b*NK + t)*2 + 1] = r1;
        outmask[(size_t)b*NK + t] = msk ? 1.0f : 0.0f;
    }
    __syncthreads();
    // ---- no more barriers: each wave owns rows m0..m0+15 end-to-end ----

    const int wid = t >> 6, lane = t & 63;
    const int lr = lane & 15, lg = lane >> 4;
    const int m0 = wid * 16;

    // ---- GEMM1: h1 = LN1(relu(xn @ Wemb^T + b_emb)) ----
    const short8 aX = *(const short8*)&s_xn[m0 + lr][8*lg];
    f32x4 acc1[8];
    #pragma unroll
    for (int nt = 0; nt < 8; ++nt) {
        const float bb = b_emb[nt*16 + lr];
        acc1[nt] = f32x4{bb, bb, bb, bb};
        const short8 bw = *(const short8*)&WembB[(nt*16 + lr)*32 + 8*lg];
        acc1[nt] = __builtin_amdgcn_mfma_f32_16x16x32_bf16(aX, bw, acc1[nt], 0, 0, 0);
    }
    #pragma unroll
    for (int r = 0; r < 4; ++r) {
        float v[8];
        float ps = 0.0f, pq = 0.0f;
        #pragma unroll
        for (int nt = 0; nt < 8; ++nt) {
            v[nt] = fmaxf(acc1[nt][r], 0.0f);
            ps += v[nt]; pq += v[nt]*v[nt];
        }
        #pragma unroll
        for (int m = 1; m <= 8; m <<= 1) { ps += __shfl_xor(ps, m, 64); pq += __shfl_xor(pq, m, 64); }
        const float mu = ps * (1.0f/128.0f);
        const float var = pq * (1.0f/128.0f) - mu*mu;
        const float rstd = rsqrtf(var + 1e-5f);
        #pragma unroll
        for (int nt = 0; nt < 8; ++nt) {
            const int c = nt*16 + lr;
            s_h1[m0 + 4*lg + r][c] = f2bf((v[nt] - mu) * rstd * ln1g[c] + ln1b[c]);
        }
    }

    // A-fragments of h1 (reused by both chunks)
    short8 a2[4];
    #pragma unroll
    for (int k0 = 0; k0 < 4; ++k0)
        a2[k0] = *(const short8*)&s_h1[m0 + lr][k0*32 + 8*lg];

    f32x4 acc3[8];
    #pragma unroll
    for (int nt = 0; nt < 8; ++nt) {
        const float bb = b2[nt*16 + lr];
        acc3[nt] = f32x4{bb, bb, bb, bb};
    }

    // ---- chunked GEMM2 (h2 = relu(h1@W1^T+b1)) -> GEMM3 accumulate ----
    #pragma unroll
    for (int cc = 0; cc < 2; ++cc) {
        #pragma unroll
        for (int nt2 = 0; nt2 < 8; ++nt2) {
            const int n = cc*128 + nt2*16 + lr;
            const float bb = b1[n];
            f32x4 acc2 = f32x4{bb, bb, bb, bb};
            #pragma unroll
            for (int k0 = 0; k0 < 4; ++k0) {
                const short8 bw = *(const short8*)&W1B[n*DM + k0*32 + 8*lg];
                acc2 = __builtin_amdgcn_mfma_f32_16x16x32_bf16(a2[k0], bw, acc2, 0, 0, 0);
            }
            #pragma unroll
            for (int r = 0; r < 4; ++r)
                s_h2c[m0 + 4*lg + r][nt2*16 + lr] = f2bf(fmaxf(acc2[r], 0.0f));
        }
        short8 a3[4];
        #pragma unroll
        for (int k0 = 0; k0 < 4; ++k0)
            a3[k0] = *(const short8*)&s_h2c[m0 + lr][k0*32 + 8*lg];
        #pragma unroll
        for (int nt3 = 0; nt3 < 8; ++nt3) {
            const int n = nt3*16 + lr;
            #pragma unroll
            for (int k0 = 0; k0 < 4; ++k0) {
                const short8 bw = *(const short8*)&W2B[n*DFF + cc*128 + k0*32 + 8*lg];
                acc3[nt3] = __builtin_amdgcn_mfma_f32_16x16x32_bf16(a3[k0], bw, acc3[nt3], 0, 0, 0);
            }
        }
    }

    // ---- phase 6: residual + LN2 + mask + store ----
    #pragma unroll
    for (int r = 0; r < 4; ++r) {
        const int row = m0 + 4*lg + r;
        const float keep = bf2f(s_xn[row][19]);
        float v[8];
        float ps = 0.0f, pq = 0.0f;
        #pragma unroll
        for (int nt = 0; nt < 8; ++nt) {
            const float h1v = bf2f(s_h1[row][nt*16 + lr]);
            const float xv = h1v + fmaxf(acc3[nt][r], 0.0f);
            v[nt] = xv; ps += xv; pq += xv*xv;
        }
        #pragma unroll
        for (int m = 1; m <= 8; m <<= 1) { ps += __shfl_xor(ps, m, 64); pq += __shfl_xor(pq, m, 64); }
        const float mu = ps * (1.0f/128.0f);
        const float var = pq * (1.0f/128.0f) - mu*mu;
        const float rstd = rsqrtf(var + 1e-5f);
        #pragma unroll
        for (int nt = 0; nt < 8; ++nt) {
            const int c = nt*16 + lr;
            out[((size_t)b*NK + row)*DM + c] = ((v[nt]-mu)*rstd*ln2g[c] + ln2b[c]) * keep;
        }
    }
}

extern "C" void kernel_launch(void* const* d_in, const int* in_sizes, int n_in,
                              void* d_out, int out_size, void* d_ws, size_t ws_size,
                              hipStream_t stream) {
    const float* x        = (const float*)d_in[0];
    const int*   idxs     = (const int*)  d_in[1];
    const float* origin   = (const float*)d_in[2];
    const float* direction= (const float*)d_in[3];
    const float* ncount   = (const float*)d_in[4];
    const float* nmean    = (const float*)d_in[5];
    const float* nsq      = (const float*)d_in[6];
    const float* W_emb    = (const float*)d_in[7];
    const float* b_emb    = (const float*)d_in[8];
    const float* ln1g     = (const float*)d_in[9];
    const float* ln1b     = (const float*)d_in[10];
    const float* W1       = (const float*)d_in[11];
    const float* b1       = (const float*)d_in[12];
    const float* W2       = (const float*)d_in[13];
    const float* b2       = (const float*)d_in[14];
    const float* ln2g     = (const float*)d_in[15];
    const float* ln2b     = (const float*)d_in[16];

    float* out     = (float*)d_out;
    float* outrel  = out    + (size_t)NB*NK*DM;
    float* outmask = outrel + (size_t)NB*NK*2;

    ushort* WembB = (ushort*)d_ws;          // 128*32
    ushort* W1B   = WembB + DM*32;          // 256*128
    ushort* W2B   = W1B   + DFF*DM;         // 128*256

    convert_weights<<<128, 256, 0, stream>>>(W_emb, W1, W2, WembB, W1B, W2B);
    itemblock_kernel<<<NB, 256, 0, stream>>>(x, idxs, origin, direction, ncount,
        nmean, nsq, b_emb, ln1g, ln1b, b1, b2, ln2g, ln2b,
        WembB, W1B, W2B, out, outrel, outmask);
}

// Round 3
// 181.730 us; speedup vs baseline: 10.1392x; 1.5302x over previous
//
#include <hip/hip_runtime.h>
#include <math.h>

#define NB 4096
#define NN 256
#define NF 16
#define NK 64
#define DIN 19
#define DM 128
#define DFF 256
#define MLP_BLOCKS 512
#define BPB 8   // batches per mlp block

using short8 = __attribute__((ext_vector_type(8))) short;
using f32x4  = __attribute__((ext_vector_type(4))) float;

__device__ inline ushort f2bf(float f) {
    unsigned u = __float_as_uint(f);
    return (ushort)((u + 0x7fffu + ((u >> 16) & 1u)) >> 16);
}
__device__ inline float bf2f(ushort h) {
    return __uint_as_float(((unsigned)h) << 16);
}
// XOR swizzle: spreads row-strided accesses across 8 16B slots (bank-conflict-free)
__device__ inline int swz(int row, int colShorts, int pitchShorts) {
    const int byte = (row * pitchShorts + colShorts) * 2;
    return byte ^ ((row & 7) << 4);
}

// ---- pre-kernel: convert weights to bf16 in workspace ----
__global__ void convert_weights(const float* __restrict__ W_emb,
                                const float* __restrict__ W1,
                                const float* __restrict__ W2,
                                ushort* __restrict__ WembB,
                                ushort* __restrict__ W1B,
                                ushort* __restrict__ W2B) {
    const int i = blockIdx.x * 256 + threadIdx.x;   // 0..32767
    if (i < DM * 32) {
        const int n = i >> 5, k = i & 31;
        WembB[i] = f2bf(k < DIN ? W_emb[n * DIN + k] : 0.0f);
    }
    W1B[i] = f2bf(W1[i]);
    W2B[i] = f2bf(W2[i]);
}

// ---- kernel 1: top-K select + feature build (high occupancy, latency-tolerant) ----
__global__ __launch_bounds__(256) void select_kernel(
    const float* __restrict__ x, const int* __restrict__ idxs,
    const float* __restrict__ origin, const float* __restrict__ direction,
    const float* __restrict__ norm_count, const float* __restrict__ norm_mean,
    const float* __restrict__ norm_sqsum,
    ushort* __restrict__ xnB, float* __restrict__ outrel, float* __restrict__ outmask)
{
    __shared__ unsigned long long s_keys[NN];
    const int b = blockIdx.x;
    const int t = threadIdx.x;

    const float dirx = direction[b*2+0], diry = direction[b*2+1];
    const float ang = -atan2f(diry, dirx);
    const float cr = cosf(ang), sr = sinf(ang);
    const float ox = origin[b*2+0], oy = origin[b*2+1];

    {
        const int j = idxs[b*NN + t];
        const float4 xr = *reinterpret_cast<const float4*>(x + (size_t)j*NF);
        const float dx = xr.x - ox, dy = xr.y - oy;
        const float r0 = cr*dx - sr*dy;
        const float r1 = sr*dx + cr*dy;
        const float dist = sqrtf(r0*r0 + r1*r1);
        const float key = -dist - ((xr.z == 0.0f) ? 1e8f : 0.0f);
        unsigned u = __float_as_uint(key);
        u = (u & 0x80000000u) ? ~u : (u | 0x80000000u);
        s_keys[t] = ((unsigned long long)(~u) << 32) | (unsigned)t;
    }
    __syncthreads();

    for (int sz = 2; sz <= NN; sz <<= 1) {
        for (int st = sz >> 1; st > 0; st >>= 1) {
            const int ixj = t ^ st;
            if (ixj > t) {
                const unsigned long long a = s_keys[t];
                const unsigned long long c = s_keys[ixj];
                const bool up = ((t & sz) == 0);
                if ((a > c) == up) { s_keys[t] = c; s_keys[ixj] = a; }
            }
            __syncthreads();
        }
    }

    if (t < NK) {
        const int p = (int)(s_keys[t] & 0xFFFFFFFFull);
        const int j = idxs[b*NN + p];
        const float4* xrow = reinterpret_cast<const float4*>(x + (size_t)j*NF);
        const float4 a0 = xrow[0], a1 = xrow[1], a2 = xrow[2], a3 = xrow[3];
        float xc[DIN];
        xc[0]=a0.x; xc[1]=a0.y; xc[2]=a0.z; xc[3]=a0.w;
        xc[4]=a1.x; xc[5]=a1.y; xc[6]=a1.z; xc[7]=a1.w;
        xc[8]=a2.x; xc[9]=a2.y; xc[10]=a2.z; xc[11]=a2.w;
        xc[12]=a3.x; xc[13]=a3.y; xc[14]=a3.z; xc[15]=a3.w;
        const float dx = xc[0]-ox, dy = xc[1]-oy;
        const float r0 = cr*dx - sr*dy;
        const float r1 = sr*dx + cr*dy;
        const float dist = sqrtf(r0*r0 + r1*r1);
        const float inv = 1.0f / (dist + 1e-8f);
        xc[16] = r0*inv; xc[17] = r1*inv; xc[18] = sqrtf(dist);
        const float cnt = norm_count[0];
        union { ushort us[32]; int4 v4[4]; } u;
        #pragma unroll
        for (int f = 0; f < DIN; ++f) {
            float sd = sqrtf(norm_sqsum[f] / (cnt - 1.0f));
            sd = (sd == 0.0f) ? 1.0f : sd;
            float v = (xc[f] - norm_mean[f]) / sd;
            v = fminf(fmaxf(v, -5.0f), 5.0f);
            u.us[f] = f2bf(v);
        }
        #pragma unroll
        for (int f = DIN; f < 32; ++f) u.us[f] = 0;
        int4* dst = reinterpret_cast<int4*>(xnB + ((size_t)b*NK + t)*32);
        dst[0] = u.v4[0]; dst[1] = u.v4[1]; dst[2] = u.v4[2]; dst[3] = u.v4[3];
        const bool msk = (xc[2] == 0.0f);
        outrel[((size_t)b*NK + t)*2 + 0] = r0;
        outrel[((size_t)b*NK + t)*2 + 1] = r1;
        outmask[(size_t)b*NK + t] = msk ? 1.0f : 0.0f;
    }
}

// ---- kernel 2: MLP with weights resident in LDS, batch loop, zero inner barriers ----
__global__ __launch_bounds__(256, 1) void mlp_kernel(
    const float* __restrict__ b_emb, const float* __restrict__ ln1g,
    const float* __restrict__ ln1b, const float* __restrict__ b1,
    const float* __restrict__ b2, const float* __restrict__ ln2g,
    const float* __restrict__ ln2b,
    const ushort* __restrict__ WembB, const ushort* __restrict__ W1B,
    const ushort* __restrict__ W2B, const ushort* __restrict__ xnB,
    const float* __restrict__ outmask, float* __restrict__ out)
{
    __shared__ __align__(16) ushort s_w1[DFF * DM];   // 64 KB, swizzled pitch 128
    __shared__ __align__(16) ushort s_w2[DM * DFF];   // 64 KB, swizzled pitch 256
    __shared__ __align__(16) ushort s_h1[NK * DM];    // 16 KB, swizzled pitch 128
    __shared__ __align__(16) ushort s_h2[NK * 64];    //  8 KB, swizzled pitch 64
    // total 152 KB -> 1 block/CU

    const int t = threadIdx.x;

    // stage W1 (pitch 256 B/row) and W2 (pitch 512 B/row) into swizzled LDS
    {
        const int4* g1 = reinterpret_cast<const int4*>(W1B);
        #pragma unroll
        for (int j = 0; j < 16; ++j) {
            const int blk = j*256 + t;
            const int byte = blk * 16;
            const int row = byte >> 8;
            *reinterpret_cast<int4*>((char*)s_w1 + (byte ^ ((row & 7) << 4))) = g1[blk];
        }
        const int4* g2 = reinterpret_cast<const int4*>(W2B);
        #pragma unroll
        for (int j = 0; j < 16; ++j) {
            const int blk = j*256 + t;
            const int byte = blk * 16;
            const int row = byte >> 9;
            *reinterpret_cast<int4*>((char*)s_w2 + (byte ^ ((row & 7) << 4))) = g2[blk];
        }
    }
    __syncthreads();

    const int lane = t & 63;
    const int lr = lane & 15, lg = lane >> 4;
    const int m0 = (t >> 6) * 16;

    for (int bi = 0; bi < BPB; ++bi) {
        const int b = blockIdx.x * BPB + bi;

        // A fragment of xn from global (L2-resident, coalesced 16B/lane)
        const short8 aX = *reinterpret_cast<const short8*>(
            xnB + ((size_t)b*NK + m0 + lr)*32 + 8*lg);

        // ---- GEMM1 + LN1 -> s_h1 ----
        f32x4 acc1[8];
        #pragma unroll
        for (int nt = 0; nt < 8; ++nt) {
            const float bb = b_emb[nt*16 + lr];
            acc1[nt] = f32x4{bb, bb, bb, bb};
            const short8 bw = *reinterpret_cast<const short8*>(
                WembB + (nt*16 + lr)*32 + 8*lg);
            acc1[nt] = __builtin_amdgcn_mfma_f32_16x16x32_bf16(aX, bw, acc1[nt], 0, 0, 0);
        }
        #pragma unroll
        for (int r = 0; r < 4; ++r) {
            float v[8];
            float ps = 0.0f, pq = 0.0f;
            #pragma unroll
            for (int nt = 0; nt < 8; ++nt) {
                v[nt] = fmaxf(acc1[nt][r], 0.0f);
                ps += v[nt]; pq += v[nt]*v[nt];
            }
            #pragma unroll
            for (int m = 1; m <= 8; m <<= 1) { ps += __shfl_xor(ps, m, 64); pq += __shfl_xor(pq, m, 64); }
            const float mu = ps * (1.0f/128.0f);
            const float var = pq * (1.0f/128.0f) - mu*mu;
            const float rstd = rsqrtf(var + 1e-5f);
            const int row = m0 + 4*lg + r;
            #pragma unroll
            for (int nt = 0; nt < 8; ++nt) {
                const int c = nt*16 + lr;
                *reinterpret_cast<ushort*>((char*)s_h1 + swz(row, c, DM)) =
                    f2bf((v[nt] - mu) * rstd * ln1g[c] + ln1b[c]);
            }
        }

        short8 a2[4];
        #pragma unroll
        for (int k0 = 0; k0 < 4; ++k0)
            a2[k0] = *reinterpret_cast<const short8*>(
                (char*)s_h1 + swz(m0 + lr, k0*32 + 8*lg, DM));

        f32x4 acc3[8];
        #pragma unroll
        for (int nt = 0; nt < 8; ++nt) {
            const float bb = b2[nt*16 + lr];
            acc3[nt] = f32x4{bb, bb, bb, bb};
        }

        // ---- GEMM2 (64-col chunks) -> GEMM3 accumulate ----
        #pragma unroll
        for (int cc = 0; cc < 4; ++cc) {
            #pragma unroll
            for (int nt2 = 0; nt2 < 4; ++nt2) {
                const int n = cc*64 + nt2*16 + lr;
                const float bb = b1[n];
                f32x4 acc2 = f32x4{bb, bb, bb, bb};
                #pragma unroll
                for (int k0 = 0; k0 < 4; ++k0) {
                    const short8 bw = *reinterpret_cast<const short8*>(
                        (char*)s_w1 + swz(n, k0*32 + 8*lg, DM));
                    acc2 = __builtin_amdgcn_mfma_f32_16x16x32_bf16(a2[k0], bw, acc2, 0, 0, 0);
                }
                #pragma unroll
                for (int r = 0; r < 4; ++r)
                    *reinterpret_cast<ushort*>(
                        (char*)s_h2 + swz(m0 + 4*lg + r, nt2*16 + lr, 64)) =
                        f2bf(fmaxf(acc2[r], 0.0f));
            }
            short8 a3[2];
            #pragma unroll
            for (int kc = 0; kc < 2; ++kc)
                a3[kc] = *reinterpret_cast<const short8*>(
                    (char*)s_h2 + swz(m0 + lr, kc*32 + 8*lg, 64));
            #pragma unroll
            for (int nt3 = 0; nt3 < 8; ++nt3) {
                const int n = nt3*16 + lr;
                #pragma unroll
                for (int kc = 0; kc < 2; ++kc) {
                    const short8 bw = *reinterpret_cast<const short8*>(
                        (char*)s_w2 + swz(n, cc*64 + kc*32 + 8*lg, DFF));
                    acc3[nt3] = __builtin_amdgcn_mfma_f32_16x16x32_bf16(a3[kc], bw, acc3[nt3], 0, 0, 0);
                }
            }
        }

        // ---- residual + LN2 + mask + store ----
        #pragma unroll
        for (int r = 0; r < 4; ++r) {
            const int row = m0 + 4*lg + r;
            const float keep = 1.0f - outmask[(size_t)b*NK + row];
            float v[8];
            float ps = 0.0f, pq = 0.0f;
            #pragma unroll
            for (int nt = 0; nt < 8; ++nt) {
                const float h1v = bf2f(*reinterpret_cast<const ushort*>(
                    (const char*)s_h1 + swz(row, nt*16 + lr, DM)));
                const float xv = h1v + fmaxf(acc3[nt][r], 0.0f);
                v[nt] = xv; ps += xv; pq += xv*xv;
            }
            #pragma unroll
            for (int m = 1; m <= 8; m <<= 1) { ps += __shfl_xor(ps, m, 64); pq += __shfl_xor(pq, m, 64); }
            const float mu = ps * (1.0f/128.0f);
            const float var = pq * (1.0f/128.0f) - mu*mu;
            const float rstd = rsqrtf(var + 1e-5f);
            #pragma unroll
            for (int nt = 0; nt < 8; ++nt) {
                const int c = nt*16 + lr;
                out[((size_t)b*NK + row)*DM + c] = ((v[nt]-mu)*rstd*ln2g[c] + ln2b[c]) * keep;
            }
        }
    }
}

extern "C" void kernel_launch(void* const* d_in, const int* in_sizes, int n_in,
                              void* d_out, int out_size, void* d_ws, size_t ws_size,
                              hipStream_t stream) {
    const float* x        = (const float*)d_in[0];
    const int*   idxs     = (const int*)  d_in[1];
    const float* origin   = (const float*)d_in[2];
    const float* direction= (const float*)d_in[3];
    const float* ncount   = (const float*)d_in[4];
    const float* nmean    = (const float*)d_in[5];
    const float* nsq      = (const float*)d_in[6];
    const float* W_emb    = (const float*)d_in[7];
    const float* b_emb    = (const float*)d_in[8];
    const float* ln1g     = (const float*)d_in[9];
    const float* ln1b     = (const float*)d_in[10];
    const float* W1       = (const float*)d_in[11];
    const float* b1       = (const float*)d_in[12];
    const float* W2       = (const float*)d_in[13];
    const float* b2       = (const float*)d_in[14];
    const float* ln2g     = (const float*)d_in[15];
    const float* ln2b     = (const float*)d_in[16];

    float* out     = (float*)d_out;
    float* outrel  = out    + (size_t)NB*NK*DM;
    float* outmask = outrel + (size_t)NB*NK*2;

    ushort* WembB = (ushort*)d_ws;              // 128*32
    ushort* W1B   = WembB + DM*32;              // 256*128
    ushort* W2B   = W1B   + DFF*DM;             // 128*256
    ushort* xnB   = W2B   + DM*DFF;             // 4096*64*32 (16 MB)

    convert_weights<<<128, 256, 0, stream>>>(W_emb, W1, W2, WembB, W1B, W2B);
    select_kernel<<<NB, 256, 0, stream>>>(x, idxs, origin, direction, ncount,
        nmean, nsq, xnB, outrel, outmask);
    mlp_kernel<<<MLP_BLOCKS, 256, 0, stream>>>(b_emb, ln1g, ln1b, b1, b2,
        ln2g, ln2b, WembB, W1B, W2B, xnB, outmask, out);
}